// Round 7
// baseline (4342.282 us; speedup 1.0000x reference)
//
#include <hip/hip_runtime.h>
#include <hip/hip_bf16.h>
#include <cstdio>
#include <math.h>

// GraphAttention forward, MI355X/gfx950.  Inputs/outputs FLOAT32.
// out0: bf16 MFMA path (PASSES at 2e-2).
// out1: R4-R6 established the np reference is FLOAT32 (full-fp64 pipeline with
// 1e-13-class exactness still flips >=1 of 8.4M binary decisions; min true
// margin 1.26e-9). This round EMULATES numpy-fp32 arithmetic bit-for-bit where
// its structure is known:
//   - einsum sums (feats over f, logits over k, temp over j): buffered-einsum
//     contiguous SOP = SSE 4-lane 1-acc dot, lane = idx%4, hsum ((a0+a1)+(a2+a3))
//   - np.sum reductions (softmax S over 256, s over 16384): numpy pairwise_sum,
//     AVX512 base case (8 chunk-accs x 16 lanes, _mm512_reduce_add_ps tree)
//   - exp/sigmoid: correctly-rounded fp32 via fp64 exp
//   - all fp32 ops via __f*_rn (no FMA contraction)

typedef __attribute__((ext_vector_type(8))) short   s16x8;
typedef __attribute__((ext_vector_type(8))) __bf16  bf16x8;
typedef __attribute__((ext_vector_type(4))) float   fx4;

#define FADD __fadd_rn
#define FMUL __fmul_rn
#define FSUB __fsub_rn
#define FDIV __fdiv_rn
#define MASKC (-9999998976.0f)   // fl32(-1e10)

__device__ __forceinline__ fx4 mfma_bf16_16x16x32(s16x8 a, s16x8 b, fx4 c) {
    return __builtin_amdgcn_mfma_f32_16x16x32_bf16(
        __builtin_bit_cast(bf16x8, a), __builtin_bit_cast(bf16x8, b), c, 0, 0, 0);
}
__device__ __forceinline__ unsigned short f2bf(float f) {
    unsigned int x = __builtin_bit_cast(unsigned int, f);
    unsigned int lsb = (x >> 16) & 1u;
    x += 0x7fffu + lsb;
    return (unsigned short)(x >> 16);
}
__device__ __forceinline__ unsigned int pack2(float a, float b) {
    return (unsigned int)f2bf(a) | ((unsigned int)f2bf(b) << 16);
}
__device__ __forceinline__ float expf_cr(float x) {   // correctly-rounded expf
    return (float)exp((double)x);
}

// numpy pairwise_sum base (n=128), AVX512 flavor:
// 8 chunk-accumulators (16 lanes), combine ((r0+r1)+(r2+r3))+((r4+r5)+(r6+r7)),
// then _mm512_reduce_add_ps halving tree.
__device__ float pw128(const float* a) {
    float c[16];
#pragma unroll
    for (int l = 0; l < 16; ++l) {
        float t0 = FADD(FADD(a[l], a[16 + l]), FADD(a[32 + l], a[48 + l]));
        float t1 = FADD(FADD(a[64 + l], a[80 + l]), FADD(a[96 + l], a[112 + l]));
        c[l] = FADD(t0, t1);
    }
    float d[8], e[4], f[2];
#pragma unroll
    for (int l = 0; l < 8; ++l) d[l] = FADD(c[l], c[l + 8]);
#pragma unroll
    for (int l = 0; l < 4; ++l) e[l] = FADD(d[l], d[l + 4]);
#pragma unroll
    for (int l = 0; l < 2; ++l) f[l] = FADD(e[l], e[l + 2]);
    return FADD(f[0], f[1]);
}

// ---------------------------------------------------------------- out0 support
__global__ __launch_bounds__(256) void repack_w(const float* __restrict__ kern,
                                                unsigned short* __restrict__ wkt) {
    int t = blockIdx.x * 256 + threadIdx.x;
    int n = t >> 9, f = t & 511;
    int h = n >> 6, k = n & 63;
    wkt[t] = f2bf(kern[(h * 512 + f) * 64 + k]);
}

#define BK 32
__global__ __launch_bounds__(256) void gemm_feats(const float* __restrict__ X,
                                                  const unsigned short* __restrict__ Wkt,
                                                  unsigned short* __restrict__ feats_bf) {
    __shared__ alignas(16) unsigned short As[128 * BK];
    __shared__ alignas(16) unsigned short Bs[128 * BK];
    const int tid = threadIdx.x;
    const int mb = blockIdx.x >> 2, nb = blockIdx.x & 3;
    const int m0 = mb * 128, n0 = nb * 128;
    const int w = tid >> 6, lane = tid & 63;
    const int mw = (w & 1) * 64, nw = (w >> 1) * 64;
    const int lr = lane & 15, lq = lane >> 4;
    const int srow = tid >> 2, scol = (tid & 3) * 8;

    fx4 acc[4][4] = {};
    for (int k0 = 0; k0 < 512; k0 += BK) {
        __syncthreads();
        {
            const float* xr0 = &X[(m0 + srow) * 512 + k0 + scol];
            const float* xr1 = &X[(m0 + srow + 64) * 512 + k0 + scol];
            float4 a0 = *(const float4*)xr0, a1 = *(const float4*)(xr0 + 4);
            float4 b0 = *(const float4*)xr1, b1 = *(const float4*)(xr1 + 4);
            uint4 p0 = { pack2(a0.x, a0.y), pack2(a0.z, a0.w), pack2(a1.x, a1.y), pack2(a1.z, a1.w) };
            uint4 p1 = { pack2(b0.x, b0.y), pack2(b0.z, b0.w), pack2(b1.x, b1.y), pack2(b1.z, b1.w) };
            *(uint4*)&As[srow * BK + scol]        = p0;
            *(uint4*)&As[(srow + 64) * BK + scol] = p1;
            *(uint4*)&Bs[srow * BK + scol]        = *(const uint4*)&Wkt[(n0 + srow) * 512 + k0 + scol];
            *(uint4*)&Bs[(srow + 64) * BK + scol] = *(const uint4*)&Wkt[(n0 + srow + 64) * 512 + k0 + scol];
        }
        __syncthreads();
        s16x8 a[4], bb[4];
#pragma unroll
        for (int i = 0; i < 4; ++i) a[i]  = *(const s16x8*)&As[(mw + i * 16 + lr) * BK + lq * 8];
#pragma unroll
        for (int i = 0; i < 4; ++i) bb[i] = *(const s16x8*)&Bs[(nw + i * 16 + lr) * BK + lq * 8];
#pragma unroll
        for (int i = 0; i < 4; ++i)
#pragma unroll
            for (int j = 0; j < 4; ++j)
                acc[i][j] = mfma_bf16_16x16x32(a[i], bb[j], acc[i][j]);
    }
#pragma unroll
    for (int i = 0; i < 4; ++i)
#pragma unroll
        for (int j = 0; j < 4; ++j) {
            int col  = n0 + nw + j * 16 + lr;
            int rowb = m0 + mw + i * 16 + lq * 4;
#pragma unroll
            for (int r = 0; r < 4; ++r)
                feats_bf[(rowb + r) * 512 + col] = f2bf(acc[i][j][r]);
        }
}

// ---------------------------------------------------------------- feats32 (np emu)
// feats32[h][row][k] = SSE-dot over f: lane = f%4, acc_l += x*w (order f, f+4), hsum
__global__ __launch_bounds__(256) void feats32_emu(const float* __restrict__ X,
                                                   const float* __restrict__ kern,
                                                   float* __restrict__ feats32) {
    int t = blockIdx.x * 256 + threadIdx.x;      // 16,777,216
    int k = t & 63, row = (t >> 6) & 32767, h = t >> 21;
    const float* xr = &X[row * 512];
    const float* kp = &kern[(h * 512) * 64 + k];  // stride 64 over f
    float a0 = 0.f, a1 = 0.f, a2 = 0.f, a3 = 0.f;
    for (int f = 0; f < 512; f += 8) {
        a0 = FADD(a0, FMUL(xr[f + 0], kp[(f + 0) * 64]));
        a1 = FADD(a1, FMUL(xr[f + 1], kp[(f + 1) * 64]));
        a2 = FADD(a2, FMUL(xr[f + 2], kp[(f + 2) * 64]));
        a3 = FADD(a3, FMUL(xr[f + 3], kp[(f + 3) * 64]));
        a0 = FADD(a0, FMUL(xr[f + 4], kp[(f + 4) * 64]));
        a1 = FADD(a1, FMUL(xr[f + 5], kp[(f + 5) * 64]));
        a2 = FADD(a2, FMUL(xr[f + 6], kp[(f + 6) * 64]));
        a3 = FADD(a3, FMUL(xr[f + 7], kp[(f + 7) * 64]));
    }
    feats32[t] = FADD(FADD(a0, a1), FADD(a2, a3));
}

// ---------------------------------------------------------------- logits (np emu)
__device__ float sse_dot64(const float* __restrict__ x, const float* __restrict__ y) {
    float a0 = 0.f, a1 = 0.f, a2 = 0.f, a3 = 0.f;
    for (int i = 0; i < 64; i += 8) {
        a0 = FADD(a0, FMUL(x[i + 0], y[i + 0]));
        a1 = FADD(a1, FMUL(x[i + 1], y[i + 1]));
        a2 = FADD(a2, FMUL(x[i + 2], y[i + 2]));
        a3 = FADD(a3, FMUL(x[i + 3], y[i + 3]));
        a0 = FADD(a0, FMUL(x[i + 4], y[i + 4]));
        a1 = FADD(a1, FMUL(x[i + 5], y[i + 5]));
        a2 = FADD(a2, FMUL(x[i + 6], y[i + 6]));
        a3 = FADD(a3, FMUL(x[i + 7], y[i + 7]));
    }
    return FADD(FADD(a0, a1), FADD(a2, a3));
}

__global__ __launch_bounds__(256) void logits_emu(const float* __restrict__ feats32,
                                                  const float* __restrict__ attn_s,
                                                  const float* __restrict__ attn_n,
                                                  float* __restrict__ a_s32,
                                                  float* __restrict__ a_n32) {
    int t = blockIdx.x * 256 + threadIdx.x;      // 262,144
    int row = t & 32767, h = t >> 15;
    const float* fr = &feats32[(h * 32768 + row) * 64];
    a_s32[h * 32768 + row] = sse_dot64(fr, &attn_s[h * 64]);
    a_n32[h * 32768 + row] = sse_dot64(fr, &attn_n[h * 64]);
}

// ---------------------------------------------------------------- attention (np-fp32 emu)
#define VT_STRIDE 264
#define AS_STRIDE 264
__global__ __launch_bounds__(256) void attn_emu(const float* __restrict__ A,
                                                const unsigned short* __restrict__ feats_bf,
                                                const float* __restrict__ a_s32,
                                                const float* __restrict__ a_n32,
                                                const float* __restrict__ biases,
                                                float* __restrict__ out0,
                                                float* __restrict__ view32) {
    __shared__ alignas(16) unsigned short Vt[64 * VT_STRIDE];   // 33792 B
    __shared__ alignas(4)  unsigned char  Asm[64 * AS_STRIDE];  // 16896 B
    __shared__ float an_l[8][256];                              //  8192 B
    __shared__ float as_l[8][64];                               //  2048 B
    __shared__ float Msh[8][64];                                //  2048 B
    __shared__ float Ssh[8][64];                                //  2048 B  = 65024 B

    const int tid = threadIdx.x;
    const int b = blockIdx.x >> 2;
    const int row0 = (blockIdx.x & 3) * 64;
    const int w = tid >> 6, lane = tid & 63;
    const int m = lane & 15, jq = lane >> 4;

    // stage adjacency as bytes
#pragma unroll
    for (int l = 0; l < 16; ++l) {
        int lin = tid + l * 256;
        int i = lin >> 6, jf = lin & 63;
        float4 av = *(const float4*)&A[(((b << 8) + row0 + i) << 8) + jf * 4];
        unsigned int bits = (av.x != 0.f ? 1u : 0u) | (av.y != 0.f ? 0x100u : 0u) |
                            (av.z != 0.f ? 0x10000u : 0u) | (av.w != 0.f ? 0x1000000u : 0u);
        *(unsigned int*)&Asm[i * AS_STRIDE + jf * 4] = bits;
    }
    // stage logits (all heads)
    for (int idx = tid; idx < 2048; idx += 256) {
        int h = idx >> 8, j = idx & 255;
        an_l[h][j] = a_n32[h * 32768 + (b << 8) + j];
    }
    for (int idx = tid; idx < 512; idx += 256) {
        int h = idx >> 6, i = idx & 63;
        as_l[h][i] = a_s32[h * 32768 + (b << 8) + row0 + i];
    }
    __syncthreads();

    // Phase A: per (i, h) task — np-fp32 M and pairwise-S
#pragma unroll
    for (int rep = 0; rep < 2; ++rep) {
        int task = tid + rep * 256;              // 0..511
        int i = task & 63, h = task >> 6;
        float asv = as_l[h][i];
        const unsigned char* arow = &Asm[i * AS_STRIDE];
        float M = -3.4e38f;
        for (int j = 0; j < 256; ++j) {
            float lg = FADD(asv, an_l[h][j]);
            float lr = lg > 0.f ? lg : FMUL(0.2f, lg);
            float v  = arow[j] ? lr : FADD(lr, MASKC);
            M = fmaxf(M, v);
        }
        float S = 0.f;
#pragma unroll
        for (int blk = 0; blk < 2; ++blk) {
            int j0 = blk * 128;
            float c[16];
#pragma unroll
            for (int l = 0; l < 16; ++l) {
                float ev[8];
#pragma unroll
                for (int q = 0; q < 8; ++q) {
                    int j = j0 + q * 16 + l;
                    float lg = FADD(asv, an_l[h][j]);
                    float lr = lg > 0.f ? lg : FMUL(0.2f, lg);
                    float v  = arow[j] ? lr : FADD(lr, MASKC);
                    ev[q] = expf_cr(FSUB(v, M));
                }
                float t0 = FADD(FADD(ev[0], ev[1]), FADD(ev[2], ev[3]));
                float t1 = FADD(FADD(ev[4], ev[5]), FADD(ev[6], ev[7]));
                c[l] = FADD(t0, t1);
            }
            float d[8], e4[4], f2[2];
#pragma unroll
            for (int l = 0; l < 8; ++l) d[l] = FADD(c[l], c[l + 8]);
#pragma unroll
            for (int l = 0; l < 4; ++l) e4[l] = FADD(d[l], d[l + 4]);
#pragma unroll
            for (int l = 0; l < 2; ++l) f2[l] = FADD(e4[l], e4[l + 2]);
            float blkS = FADD(f2[0], f2[1]);
            S = (blk == 0) ? blkS : FADD(S, blkS);
        }
        Msh[h][i] = M;
        Ssh[h][i] = S;
    }
    __syncthreads();

    // Phase B: per head — p (np-fp32), view accumulate, PV MFMA for out0
    float view_acc[8][8] = {};
    const int myrow = row0 + w * 16 + m;
    const int i_ln = w * 16 + m;
    const unsigned char* arow = &Asm[i_ln * AS_STRIDE];

    for (int h = 0; h < 8; ++h) {
        __syncthreads();
        {
            int kk = lane, jb = w;
            for (int it = 0; it < 64; ++it) {
                int j = jb * 64 + it;
                Vt[kk * VT_STRIDE + j] = feats_bf[(((b << 8) + j) << 9) + (h << 6) + kk];
            }
        }
        __syncthreads();

        float asv = as_l[h][i_ln];
        float Mi = Msh[h][i_ln];
        float Si = Ssh[h][i_ln];

        s16x8 pfrag[8];
#pragma unroll
        for (int kb = 0; kb < 8; ++kb) {
            int jbase = kb * 32 + jq * 8;
            s16x8 pf;
#pragma unroll
            for (int t = 0; t < 8; ++t) {
                int j = jbase + t;
                float lg = FADD(asv, an_l[h][j]);
                float lr = lg > 0.f ? lg : FMUL(0.2f, lg);
                float v  = arow[j] ? lr : FADD(lr, MASKC);
                float e  = expf_cr(FSUB(v, Mi));
                float p  = FDIV(e, Si);
                view_acc[kb][t] = FADD(view_acc[kb][t], FMUL(p, 0.125f));
                pf[t] = (short)f2bf(p);
            }
            pfrag[kb] = pf;
        }

        fx4 acc[4] = {};
#pragma unroll
        for (int kb = 0; kb < 8; ++kb) {
            int jo = kb * 32 + jq * 8;
#pragma unroll
            for (int nf = 0; nf < 4; ++nf) {
                s16x8 vf = *(const s16x8*)&Vt[(nf * 16 + m) * VT_STRIDE + jo];
                acc[nf] = mfma_bf16_16x16x32(pfrag[kb], vf, acc[nf]);
            }
        }
#pragma unroll
        for (int nf = 0; nf < 4; ++nf) {
            float bias = biases[h * 64 + nf * 16 + m];
#pragma unroll
            for (int r = 0; r < 4; ++r) {
                float val = acc[nf][r] + bias;
                val = val > 0.f ? val : 0.f;
                int gi = (b << 8) + row0 + w * 16 + jq * 4 + r;
                out0[gi * 512 + h * 64 + nf * 16 + m] = val;
            }
        }
    }

#pragma unroll
    for (int kb = 0; kb < 8; ++kb) {
        int base = (((b << 8) + myrow) << 8) + kb * 32 + jq * 8;
        float4 v0, v1;
        v0.x = view_acc[kb][0]; v0.y = view_acc[kb][1]; v0.z = view_acc[kb][2]; v0.w = view_acc[kb][3];
        v1.x = view_acc[kb][4]; v1.y = view_acc[kb][5]; v1.z = view_acc[kb][6]; v1.w = view_acc[kb][7];
        *(float4*)&view32[base]     = v0;
        *(float4*)&view32[base + 4] = v1;
    }
}

// ---------------------------------------------------------------- pool / temp / thresh
__global__ __launch_bounds__(256) void pool_emu(const float* __restrict__ view32,
                                                float* __restrict__ pooled) {
    int t = blockIdx.x * 256 + threadIdx.x;      // 2,097,152
    int j = t & 127, i = (t >> 7) & 127, b = t >> 14;
    const float* p = &view32[(b << 16) + (2 * i) * 256 + 2 * j];
    pooled[t] = fmaxf(fmaxf(p[0], p[1]), fmaxf(p[256], p[257]));
}

// temp[b,i,k] = SSE dot over j=0..127: pooled row (contig) x alpha[:,k] (stride 128)
__global__ __launch_bounds__(256) void temp_emu(const float* __restrict__ pooled,
                                                const float* __restrict__ alpha,
                                                float* __restrict__ temp) {
    int t = blockIdx.x * 256 + threadIdx.x;      // 2,097,152
    int k = t & 127, i = (t >> 7) & 127, b = t >> 14;
    const float* pr = &pooled[(b << 14) + i * 128];
    const float* ap = &alpha[k];                  // stride 128 over j
    float a0 = 0.f, a1 = 0.f, a2 = 0.f, a3 = 0.f;
    for (int j = 0; j < 128; j += 8) {
        a0 = FADD(a0, FMUL(pr[j + 0], ap[(j + 0) * 128]));
        a1 = FADD(a1, FMUL(pr[j + 1], ap[(j + 1) * 128]));
        a2 = FADD(a2, FMUL(pr[j + 2], ap[(j + 2) * 128]));
        a3 = FADD(a3, FMUL(pr[j + 3], ap[(j + 3) * 128]));
        a0 = FADD(a0, FMUL(pr[j + 4], ap[(j + 4) * 128]));
        a1 = FADD(a1, FMUL(pr[j + 5], ap[(j + 5) * 128]));
        a2 = FADD(a2, FMUL(pr[j + 6], ap[(j + 6) * 128]));
        a3 = FADD(a3, FMUL(pr[j + 7], ap[(j + 7) * 128]));
    }
    temp[t] = FADD(FADD(a0, a1), FADD(a2, a3));
}

// s[b] = numpy pairwise over 16384 (128 leaves of pw128, balanced binary tree)
__global__ __launch_bounds__(128) void thresh_emu(const float* __restrict__ temp,
                                                  float* __restrict__ thresh32) {
    __shared__ float red[128];
    int l = threadIdx.x, b = blockIdx.x;
    red[l] = pw128(&temp[(b << 14) + l * 128]);
    __syncthreads();
    for (int s = 64; s >= 1; s >>= 1) {
        float v = 0.f;
        if (l < s) v = FADD(red[2 * l], red[2 * l + 1]);
        __syncthreads();
        if (l < s) red[l] = v;
        __syncthreads();
    }
    if (l == 0) {
        float sfin = red[0];
        float e = expf_cr(-sfin);                 // np.exp(-s) fp32 (correctly rounded)
        thresh32[b] = FDIV(1.0f, FADD(1.0f, e)); // 1/(1+e)
    }
}

// ---------------------------------------------------------------- binarize (fp32)
__global__ __launch_bounds__(256) void binarize_emu(const float* __restrict__ view32,
                                                    const float* __restrict__ thresh32,
                                                    float* __restrict__ out1) {
    int g = blockIdx.x * 256 + threadIdx.x;
    int e = g * 4;
    int b = e >> 16, i = (e >> 8) & 255, j = e & 255;
    float th = thresh32[b];
    float4 v = *(const float4*)&view32[e];
    float4 o;
    o.x = (FADD(v.x, (i == j + 0) ? 1.f : 0.f) < th) ? 1.f : 0.f;
    o.y = (FADD(v.y, (i == j + 1) ? 1.f : 0.f) < th) ? 1.f : 0.f;
    o.z = (FADD(v.z, (i == j + 2) ? 1.f : 0.f) < th) ? 1.f : 0.f;
    o.w = (FADD(v.w, (i == j + 3) ? 1.f : 0.f) < th) ? 1.f : 0.f;
    *(float4*)&out1[e] = o;
}

// ---------------------------------------------------------------- instrumentation
__global__ void init_stats(int* cnt, unsigned int* minbits) {
    for (int i = 0; i < 6; ++i) cnt[i] = 0;
    *minbits = 0x7f800000u;
}
__global__ __launch_bounds__(256) void margin_stats(const float* __restrict__ view32,
                                                    const float* __restrict__ thresh32,
                                                    int* __restrict__ cnt,
                                                    unsigned int* __restrict__ minbits) {
    int e = blockIdx.x * 256 + threadIdx.x;
    int b = e >> 16, i = (e >> 8) & 255, j = e & 255;
    double mv = (double)view32[e] + (i == j ? 1.0 : 0.0) - (double)thresh32[b];
    float mg = (float)fabs(mv);
    if (mg < 1e-4f) {
        atomicAdd(&cnt[0], 1);
        if (mg < 1e-5f) atomicAdd(&cnt[1], 1);
        if (mg < 1e-6f) atomicAdd(&cnt[2], 1);
        if (mg < 1e-7f) atomicAdd(&cnt[3], 1);
        if (mg < 1e-8f) atomicAdd(&cnt[4], 1);
        if (mg < 1e-9f) atomicAdd(&cnt[5], 1);
    }
    atomicMin(minbits, __builtin_bit_cast(unsigned int, mg));
}
__global__ void probe_out(const float* view32, const float* thresh32, const float* out1,
                          const int* cnt, const unsigned int* minbits) {
    int ones = 0;
    for (int i = 0; i < 4096; ++i) ones += (out1[i] == 1.0f);
    float mm = __builtin_bit_cast(float, *minbits);
    printf("[probe] thresh32[0]=%.9e (R6 fp64: 1.0433946382e-02)  view32[3]=%.9e (R6: 6.631488126e-03)\n",
           (double)thresh32[0], (double)view32[3]);
    printf("[probe] margins <1e-4:%d <1e-5:%d <1e-6:%d <1e-7:%d <1e-8:%d <1e-9:%d min=%.3e | ones=%d/4096\n",
           cnt[0], cnt[1], cnt[2], cnt[3], cnt[4], cnt[5], (double)mm, ones);
}

// ---------------------------------------------------------------- launch
static inline void ck_launch(const char* name) {
    hipError_t e = hipGetLastError();
    if (e != hipSuccess)
        fprintf(stderr, "[gat] %s launch error %d: %s\n", name, (int)e, hipGetErrorString(e));
}

extern "C" void kernel_launch(void* const* d_in, const int* in_sizes, int n_in,
                              void* d_out, int out_size, void* d_ws, size_t ws_size,
                              hipStream_t stream) {
    const float* X      = (const float*)d_in[0];
    const float* A      = (const float*)d_in[1];
    const float* kern   = (const float*)d_in[2];
    const float* biases = (const float*)d_in[3];
    const float* attn_s = (const float*)d_in[4];
    const float* attn_n = (const float*)d_in[5];
    const float* alpha  = (const float*)d_in[6];

    char* ws = (char*)d_ws;
    unsigned short* feats_bf = (unsigned short*)(ws);             //  33,554,432 B
    float*          feats32  = (float*)(ws + 33554432);           //  67,108,864 B
    float*          view32   = (float*)(ws + 100663296);          //  33,554,432 B
    float*          a_s32    = (float*)(ws + 134217728);          //   1,048,576 B
    float*          a_n32    = (float*)(ws + 135266304);          //   1,048,576 B
    float*          pooled   = (float*)(ws + 136314880);          //   8,388,608 B
    float*          temp     = (float*)(ws + 144703488);          //   8,388,608 B
    float*          thresh32 = (float*)(ws + 153092096);          //         512 B
    unsigned short* wkt      = (unsigned short*)(ws + 153092608); //     524,288 B
    int*            cnt      = (int*)(ws + 153616896);            //          64 B
    unsigned int*   minbits  = (unsigned int*)(ws + 153616960);   //           4 B

    float* out0 = (float*)d_out;
    float* out1 = out0 + 16777216;

    init_stats  <<<1, 1, 0, stream>>>(cnt, minbits);                ck_launch("init_stats");
    repack_w    <<<1024, 256, 0, stream>>>(kern, wkt);              ck_launch("repack_w");
    gemm_feats  <<<1024, 256, 0, stream>>>(X, wkt, feats_bf);       ck_launch("gemm_feats");
    feats32_emu <<<65536, 256, 0, stream>>>(X, kern, feats32);      ck_launch("feats32_emu");
    logits_emu  <<<1024, 256, 0, stream>>>(feats32, attn_s, attn_n, a_s32, a_n32);
                                                                    ck_launch("logits_emu");
    attn_emu    <<<512, 256, 0, stream>>>(A, feats_bf, a_s32, a_n32, biases, out0, view32);
                                                                    ck_launch("attn_emu");
    pool_emu    <<<8192, 256, 0, stream>>>(view32, pooled);         ck_launch("pool_emu");
    temp_emu    <<<8192, 256, 0, stream>>>(pooled, alpha, temp);    ck_launch("temp_emu");
    thresh_emu  <<<128, 128, 0, stream>>>(temp, thresh32);          ck_launch("thresh_emu");
    binarize_emu<<<8192, 256, 0, stream>>>(view32, thresh32, out1); ck_launch("binarize_emu");
    margin_stats<<<32768, 256, 0, stream>>>(view32, thresh32, cnt, minbits);
                                                                    ck_launch("margin_stats");
    probe_out   <<<1, 1, 0, stream>>>(view32, thresh32, out1, cnt, minbits);
                                                                    ck_launch("probe_out");
}